// Round 11
// baseline (578.508 us; speedup 1.0000x reference)
//
#include <hip/hip_runtime.h>
#include <math.h>

#define NT 17
#define KCAP 300
#define NITER 30
#define TR 6        // rows per register tile
#define LUMAX 1024  // max rows per type
// -1/tau * log2(e): B matrix is in base-2 log domain
#define MSCALE2 28.853900817779268f

typedef unsigned long long u64;

#define EX2(x) __builtin_amdgcn_exp2f(x)
#define LG2(x) __builtin_amdgcn_logf(x)
#if __has_builtin(__builtin_amdgcn_rcpf)
#define RCP(x) __builtin_amdgcn_rcpf(x)
#else
#define RCP(x) (1.0f / (x))
#endif

// ---- meta layout (ints at ws start, zeroed each launch) ----
// [0..16]   typeCount
// [32..48]  typeOff
// [64..95]  scatterCnt
// [96]      doneFlag

__device__ inline float selu_f(float x) {
  const float scale = 1.0507009873554804934193349852946f;
  const float alpha = 1.6732632423543772848170429916717f;
  return x > 0.f ? scale * x : scale * alpha * (EX2(x * 1.4426950408889634f) - 1.f);
}

__global__ void k_hist(const int* __restrict__ jt, int n, int* meta) {
  int i = blockIdx.x * 256 + threadIdx.x;
  if (i < n) atomicAdd(&meta[jt[i]], 1);
  __syncthreads();
  if (threadIdx.x == 0) {
    __threadfence();
    int d = atomicAdd(&meta[96], 1);
    if (d == (int)gridDim.x - 1) {
      int off = 0;
      for (int t = 0; t < NT; t++) {
        int c = __hip_atomic_load(&meta[t], __ATOMIC_RELAXED, __HIP_MEMORY_SCOPE_AGENT);
        meta[32 + t] = off;
        off += c;
      }
      __threadfence();
    }
  }
}

__global__ void k_scatter(const int* __restrict__ jt, int n, int* meta,
                          int* __restrict__ perm, int* __restrict__ tys) {
  int i = blockIdx.x * 256 + threadIdx.x;
  if (i < n) {
    int t = jt[i];
    int pos = meta[32 + t] + atomicAdd(&meta[64 + t], 1);
    perm[pos] = i;
    tys[pos] = t;
  }
}

// h = selu(emb @ W1 + b1)   (n x D) @ (D x H)
__global__ __launch_bounds__(256) void k_hgemm(const float* __restrict__ A,
    const float* __restrict__ B, const float* __restrict__ bias,
    float* __restrict__ C, int n, int D, int H) {
  __shared__ __align__(16) float As[16][68];
  __shared__ __align__(16) float Bs[16][68];
  int tid = threadIdx.x;
  int i0 = blockIdx.x * 64, j0 = blockIdx.y * 64;
  int tx = tid & 15, ty = tid >> 4;
  int aI = tid & 63, aK = (tid >> 6) << 2;
  int bJ = (tid & 15) << 2, bK = tid >> 4;
  float acc[4][4] = {};
  for (int k0 = 0; k0 < D; k0 += 16) {
    float4 av = *(const float4*)(A + (size_t)(i0 + aI) * D + k0 + aK);
    float4 bv = *(const float4*)(B + (size_t)(k0 + bK) * H + j0 + bJ);
    __syncthreads();
    As[aK + 0][aI] = av.x; As[aK + 1][aI] = av.y; As[aK + 2][aI] = av.z; As[aK + 3][aI] = av.w;
    *(float4*)(&Bs[bK][bJ]) = bv;
    __syncthreads();
#pragma unroll
    for (int kk = 0; kk < 16; kk++) {
      float4 a4 = *(float4*)(&As[kk][ty << 2]);
      float4 b4 = *(float4*)(&Bs[kk][tx << 2]);
      float aa[4] = {a4.x, a4.y, a4.z, a4.w};
      float bb[4] = {b4.x, b4.y, b4.z, b4.w};
#pragma unroll
      for (int p = 0; p < 4; p++)
#pragma unroll
        for (int q = 0; q < 4; q++)
          acc[p][q] = fmaf(aa[p], bb[q], acc[p][q]);
    }
  }
#pragma unroll
  for (int p = 0; p < 4; p++) {
    int i = i0 + (ty << 2) + p;
    float o[4];
#pragma unroll
    for (int q = 0; q < 4; q++) {
      int j = j0 + (tx << 2) + q;
      o[q] = selu_f(acc[p][q] + bias[j]);
    }
    *(float4*)(C + (size_t)i * H + j0 + (tx << 2)) = make_float4(o[0], o[1], o[2], o[3]);
  }
}

// row norms of h (n rows) and prototypes (k rows)
__global__ __launch_bounds__(256) void k_norms(const float* __restrict__ h,
    const float* __restrict__ P, float* __restrict__ hsq, float* __restrict__ psq,
    int n, int H, int k) {
  int wv = threadIdx.x >> 6, lane = threadIdx.x & 63;
  int idx = blockIdx.x * 4 + wv;
  const float* src; float* dst;
  if (idx < n) { src = h + (size_t)idx * H; dst = hsq + idx; }
  else if (idx < n + k) { int j = idx - n; src = P + (size_t)j * H; dst = psq + j; }
  else return;
  float s = 0.f;
  for (int d = lane * 4; d < H; d += 256) {
    float4 v = *(const float4*)(src + d);
    s += v.x * v.x + v.y * v.y + v.z * v.z + v.w * v.w;
  }
#pragma unroll
  for (int o = 32; o; o >>= 1) s += __shfl_xor(s, o);
  if (lane == 0) *dst = s;
}

// Ms[r][j] = -max(0, hsq+psq-2*dot)/tau * log2(e)  (base-2 domain), rows type-sorted
__global__ __launch_bounds__(256) void k_msort(const float* __restrict__ h,
    const float* __restrict__ P, const float* __restrict__ hsq,
    const float* __restrict__ psq, const int* __restrict__ perm,
    float* __restrict__ Ms, int n, int H, int k) {
  __shared__ __align__(16) float As[16][68];
  __shared__ __align__(16) float Bs[16][68];
  __shared__ int gIdx[64];
  int tid = threadIdx.x;
  int i0 = blockIdx.x * 64, j0 = blockIdx.y * 64;
  if (tid < 64) gIdx[tid] = perm[i0 + tid];
  __syncthreads();
  int tx = tid & 15, ty = tid >> 4;
  int aI = tid & 63, aK = (tid >> 6) << 2;
  int gA = gIdx[aI];
  bool bok = (j0 + aI) < k;
  const float* bRow = P + (size_t)(j0 + (bok ? aI : 0)) * H;
  float acc[4][4] = {};
  for (int k0 = 0; k0 < H; k0 += 16) {
    float4 av = *(const float4*)(h + (size_t)gA * H + k0 + aK);
    float4 bv = *(const float4*)(bRow + k0 + aK);
    __syncthreads();
    As[aK + 0][aI] = av.x; As[aK + 1][aI] = av.y; As[aK + 2][aI] = av.z; As[aK + 3][aI] = av.w;
    Bs[aK + 0][aI] = bv.x; Bs[aK + 1][aI] = bv.y; Bs[aK + 2][aI] = bv.z; Bs[aK + 3][aI] = bv.w;
    __syncthreads();
#pragma unroll
    for (int kk = 0; kk < 16; kk++) {
      float4 a4 = *(float4*)(&As[kk][ty << 2]);
      float4 b4 = *(float4*)(&Bs[kk][tx << 2]);
      float aa[4] = {a4.x, a4.y, a4.z, a4.w};
      float bb[4] = {b4.x, b4.y, b4.z, b4.w};
#pragma unroll
      for (int p = 0; p < 4; p++)
#pragma unroll
        for (int q = 0; q < 4; q++)
          acc[p][q] = fmaf(aa[p], bb[q], acc[p][q]);
    }
  }
#pragma unroll
  for (int p = 0; p < 4; p++) {
    int rr = (ty << 2) + p;
    int r = i0 + rr;
    float hq = hsq[gIdx[rr]];
#pragma unroll
    for (int q = 0; q < 4; q++) {
      int j = j0 + (tx << 2) + q;
      if (j < k) {
        float d2 = hq + psq[j] - 2.f * acc[p][q];
        d2 = fmaxf(d2, 0.f);
        Ms[(size_t)r * k + j] = -d2 * MSCALE2;
      }
    }
  }
}

// Persistent Sinkhorn, LINEAR domain, per-column max shift, one type per block.
// REFERENCE schedule: u_m = 1/(K'v_{m-1} + tm/Σu_{m-1}) — Σu published right
// after phase A's barrier (overlapping phase B), consumed at next iter's top by
// wave 15 while other waves run their first tile. 4-deep epoch slots.
__global__ __launch_bounds__(1024) void k_sink(float* __restrict__ Ms,
    const int* __restrict__ meta,
    u64* __restrict__ plD, unsigned* __restrict__ plE,
    float* __restrict__ uF, float* __restrict__ vF,
    int k, float tm_last) {
  __shared__ __align__(16) float V[KCAP];      // v~ (and c_j during prologue)
  __shared__ __align__(16) float WP[16][304];  // per-wave col partials
  __shared__ float uarr[LUMAX];
  __shared__ float SU[16];
  __shared__ float w_sh;
  __shared__ int lvl_ep;
  int tid = threadIdx.x, lane = tid & 63, wv = tid >> 6;
  int t = blockIdx.x;
  int cR = meta[t];
  int s0 = meta[32 + t];
  int nt = (cR + TR - 1) / TR;
  int laneCnt = (lane < NT) ? meta[lane] : 0;
  bool l2v = (lane + 64) < (k >> 2);  // second float4 slot valid

  // ---- prologue: column max, then K' = exp2(B - c_j) in place ----
  {
    float4 cm0 = make_float4(-3e38f, -3e38f, -3e38f, -3e38f);
    float4 cm1 = cm0;
    for (int tile = wv; tile < nt; tile += 16) {
      int r0 = tile * TR;
#pragma unroll
      for (int rr = 0; rr < TR; rr++) {
        int rc = (r0 + rr < cR) ? (r0 + rr) : r0;
        const float4* rp = (const float4*)(Ms + (size_t)(s0 + rc) * k);
        float4 a0 = rp[lane];
        cm0.x = fmaxf(cm0.x, a0.x); cm0.y = fmaxf(cm0.y, a0.y);
        cm0.z = fmaxf(cm0.z, a0.z); cm0.w = fmaxf(cm0.w, a0.w);
        if (l2v) {
          float4 a1 = rp[lane + 64];
          cm1.x = fmaxf(cm1.x, a1.x); cm1.y = fmaxf(cm1.y, a1.y);
          cm1.z = fmaxf(cm1.z, a1.z); cm1.w = fmaxf(cm1.w, a1.w);
        }
      }
    }
    *(float4*)&WP[wv][4 * lane] = cm0;
    if (l2v) *(float4*)&WP[wv][4 * (lane + 64)] = cm1;
    __syncthreads();
    if (tid < k) {
      float c = WP[0][tid];
#pragma unroll
      for (int q = 1; q < 16; q++) c = fmaxf(c, WP[q][tid]);
      V[tid] = c;
    }
    __syncthreads();
    float4 c0 = *(const float4*)&V[4 * lane];
    float4 c1 = l2v ? *(const float4*)&V[4 * (lane + 64)] : c0;
    for (int tile = wv; tile < nt; tile += 16) {
      int r0 = tile * TR;
#pragma unroll
      for (int rr = 0; rr < TR; rr++) {
        int r = r0 + rr;
        if (r < cR) {
          float4* rp = (float4*)(Ms + (size_t)(s0 + r) * k);
          float4 a0 = rp[lane];
          a0.x = EX2(a0.x - c0.x); a0.y = EX2(a0.y - c0.y);
          a0.z = EX2(a0.z - c0.z); a0.w = EX2(a0.w - c0.w);
          rp[lane] = a0;
          if (l2v) {
            float4 a1 = rp[lane + 64];
            a1.x = EX2(a1.x - c1.x); a1.y = EX2(a1.y - c1.y);
            a1.z = EX2(a1.z - c1.z); a1.w = EX2(a1.w - c1.w);
            rp[lane + 64] = a1;
          }
        }
      }
    }
  }
  __syncthreads();
  if (tid < k) V[tid] = 0.f;  // v~ init (underflow-equivalent to reference)
  if (tid == 0) { w_sh = 1.f; lvl_ep = 0; }
  __syncthreads();

  for (int m = 0; m < NITER; m++) {
    int epoch = m + 1;
    // ---- wave 15: consume Σu_{m-1} -> w_sh; signal ----
    if (wv == 15) {
      if (m > 0) {
        int slot = (m - 1) & 3;
        unsigned want = (unsigned)m;
        bool need = (lane < NT) && (laneCnt > 0);
        for (;;) {
          bool ok = !need ||
              (__hip_atomic_load(&plE[((size_t)slot * NT + lane) * 16],
                                 __ATOMIC_RELAXED, __HIP_MEMORY_SCOPE_AGENT) == want);
          if (__all(ok)) break;
          __builtin_amdgcn_s_sleep(1);
        }
        u64 a = need
            ? __hip_atomic_load(&plD[((size_t)slot * NT + lane) * 8],
                                __ATOMIC_RELAXED, __HIP_MEMORY_SCOPE_AGENT)
            : 0ull;
        float s = need ? __uint_as_float((unsigned)a) : 0.f;
#pragma unroll
        for (int o = 32; o; o >>= 1) s += __shfl_xor(s, o);
        if (lane == 0) w_sh = tm_last / s;
      }
      if (lane == 0)
        __hip_atomic_store(&lvl_ep, epoch, __ATOMIC_RELEASE, __HIP_MEMORY_SCOPE_WORKGROUP);
    }
    // ---- phase A: fused row-dot + col-acc over register tiles ----
    float w = 0.f;
    bool haveW = (wv == 15);
    if (haveW) w = w_sh;
    float su = 0.f;
    float4 acc0 = make_float4(0.f, 0.f, 0.f, 0.f);
    float4 acc1 = acc0;
    float4 v0 = *(const float4*)&V[4 * lane];
    float4 v1 = l2v ? *(const float4*)&V[4 * (lane + 64)] : make_float4(0.f, 0.f, 0.f, 0.f);
    for (int tile = wv; tile < nt; tile += 16) {
      int r0 = tile * TR;
      float4 a[TR][2];
#pragma unroll
      for (int rr = 0; rr < TR; rr++) {
        int rc = (r0 + rr < cR) ? (r0 + rr) : r0;
        const float4* rp = (const float4*)(Ms + (size_t)(s0 + rc) * k);
        a[rr][0] = rp[lane];
        a[rr][1] = l2v ? rp[lane + 64] : make_float4(0.f, 0.f, 0.f, 0.f);
      }
      float rs[TR];
#pragma unroll
      for (int rr = 0; rr < TR; rr++) {
        rs[rr] = a[rr][0].x * v0.x + a[rr][0].y * v0.y +
                 a[rr][0].z * v0.z + a[rr][0].w * v0.w +
                 a[rr][1].x * v1.x + a[rr][1].y * v1.y +
                 a[rr][1].z * v1.z + a[rr][1].w * v1.w;
      }
#pragma unroll
      for (int o = 32; o; o >>= 1) {
#pragma unroll
        for (int rr = 0; rr < TR; rr++) rs[rr] += __shfl_xor(rs[rr], o);
      }
      if (!haveW) {
        while (__hip_atomic_load(&lvl_ep, __ATOMIC_ACQUIRE, __HIP_MEMORY_SCOPE_WORKGROUP) < epoch)
          __builtin_amdgcn_s_sleep(1);
        w = w_sh;
        haveW = true;
      }
      float uu[TR];
#pragma unroll
      for (int rr = 0; rr < TR; rr++) {
        bool valid = (r0 + rr < cR);
        float u = RCP(rs[rr] + w);
        uu[rr] = valid ? u : 0.f;
        su += uu[rr];
        if (lane == 0 && valid) uarr[r0 + rr] = u;
      }
#pragma unroll
      for (int rr = 0; rr < TR; rr++) {
        acc0.x += a[rr][0].x * uu[rr]; acc0.y += a[rr][0].y * uu[rr];
        acc0.z += a[rr][0].z * uu[rr]; acc0.w += a[rr][0].w * uu[rr];
        acc1.x += a[rr][1].x * uu[rr]; acc1.y += a[rr][1].y * uu[rr];
        acc1.z += a[rr][1].z * uu[rr]; acc1.w += a[rr][1].w * uu[rr];
      }
    }
    *(float4*)&WP[wv][4 * lane] = acc0;
    if (l2v) *(float4*)&WP[wv][4 * (lane + 64)] = acc1;
    if (lane == 0) SU[wv] = su;
    __syncthreads();
    // ---- wave 15: publish Σu_m (slot m&3) — overlaps phase B merge ----
    if (wv == 15) {
      float sp = (lane < 16) ? SU[lane] : 0.f;
#pragma unroll
      for (int o = 32; o; o >>= 1) sp += __shfl_xor(sp, o);
      int slot = m & 3;
      if (lane == 0)
        __hip_atomic_store(&plD[((size_t)slot * NT + t) * 8],
                           (u64)__float_as_uint(sp),
                           __ATOMIC_RELAXED, __HIP_MEMORY_SCOPE_AGENT);
      __builtin_amdgcn_s_waitcnt(0);  // data globally visible before epoch
      if (lane == 0)
        __hip_atomic_store(&plE[((size_t)slot * NT + t) * 16], (unsigned)epoch,
                           __ATOMIC_RELAXED, __HIP_MEMORY_SCOPE_AGENT);
    }
    // ---- phase B: 16-way col merge -> v~ ----
    if (tid < k) {
      float s = WP[0][tid];
#pragma unroll
      for (int q = 1; q < 16; q++) s += WP[q][tid];
      V[tid] = RCP(s);
    }
    __syncthreads();
  }
  for (int r = tid; r < cR; r += 1024) uF[s0 + r] = uarr[r];
  for (int j = tid; j < k; j += 1024) vF[(size_t)t * k + j] = V[j];
}

// epilogue (linear): T_rj = K'_rj·u_r·v~_j; logits = ln(T+1e-8); scatter T with
// incremental o0-mod-17 (one candidate slot per float4 group).
__global__ __launch_bounds__(256) void k_epi(const float* __restrict__ Ms,
    const float* __restrict__ uF, const float* __restrict__ vF,
    const int* __restrict__ perm, const int* __restrict__ tys,
    float* __restrict__ out, int n, int k) {
  __shared__ float vals[KCAP];
  int r = blockIdx.x;
  int i = perm[r], t = tys[r];
  float u = uF[r];
  const float* Krow = Ms + (size_t)r * k;
  const float* Vrow = vF + (size_t)t * k;
  for (int j = threadIdx.x; j < k; j += 256) vals[j] = Krow[j] * u * Vrow[j];
  __syncthreads();
  float* lg = out + (size_t)i * k;
  for (int j = threadIdx.x; j < k; j += 256)
    lg[j] = LG2(vals[j] + 1e-8f) * 0.6931471805599453f;
  int ns = k * NT;
  float* Trow = out + (size_t)n * k + (size_t)i * ns;
  if ((ns & 3) == 0) {
    int n4 = ns >> 2;
    int o0 = threadIdx.x << 2;
    int rmod = o0 % NT;
    for (int g4 = threadIdx.x; g4 < n4; g4 += 256, o0 += 1024) {
      int sstar = t - rmod; if (sstar < 0) sstar += NT;
      int j = (unsigned)(o0 + sstar) / (unsigned)NT;
      float vv = vals[j < k ? j : 0];
      float4 v;
      v.x = (sstar == 0) ? vv : 0.f;
      v.y = (sstar == 1) ? vv : 0.f;
      v.z = (sstar == 2) ? vv : 0.f;
      v.w = (sstar == 3) ? vv : 0.f;
      *(float4*)(Trow + o0) = v;
      rmod += 4; if (rmod >= NT) rmod -= NT;
      rmod %= NT;
    }
  } else {
    for (int o = threadIdx.x; o < ns; o += 256) {
      int j = o / NT;
      int tt = o - j * NT;
      Trow[o] = (tt == t) ? vals[j] : 0.f;
    }
  }
}

extern "C" void kernel_launch(void* const* d_in, const int* in_sizes, int n_in,
                              void* d_out, int out_size, void* d_ws, size_t ws_size,
                              hipStream_t stream) {
  const float* emb = (const float*)d_in[0];
  const float* W1  = (const float*)d_in[1];
  const float* b1  = (const float*)d_in[2];
  const float* P   = (const float*)d_in[3];
  const int*   jt  = (const int*)d_in[4];
  (void)n_in; (void)ws_size;

  const int n = in_sizes[4];
  const int H = in_sizes[2];
  const int D = in_sizes[1] / H;
  const int k = out_size / (n * (NT + 1));
  const int nslots = k * NT;
  const float tm_last = (float)((n - nslots) > 1 ? (n - nslots) : 1);

  char* w = (char*)d_ws;
  size_t off = 0;
  auto take = [&](size_t bytes) -> char* {
    char* p = w + off;
    off = (off + bytes + 255) & ~(size_t)255;
    return p;
  };
  int*      meta = (int*)take(4096);
  int*      perm = (int*)take((size_t)n * 4);
  int*      tys  = (int*)take((size_t)n * 4);
  float*    h    = (float*)take((size_t)n * H * 4);
  float*    hsq  = (float*)take((size_t)n * 4);
  float*    psq  = (float*)take((size_t)k * 4);
  float*    Ms   = (float*)take((size_t)n * k * 4);
  u64*      plD  = (u64*)take((size_t)4 * NT * 64);
  unsigned* plE  = (unsigned*)take((size_t)4 * NT * 64);
  float*    uF   = (float*)take((size_t)n * 4);
  float*    vF   = (float*)take((size_t)NT * k * 4);

  (void)hipMemsetAsync(meta, 0, 4096, stream);
  (void)hipMemsetAsync(plE, 0, (size_t)4 * NT * 64, stream);
  k_hist<<<(n + 255) / 256, 256, 0, stream>>>(jt, n, meta);
  k_scatter<<<(n + 255) / 256, 256, 0, stream>>>(jt, n, meta, perm, tys);
  k_hgemm<<<dim3(n / 64, H / 64), dim3(256), 0, stream>>>(emb, W1, b1, h, n, D, H);
  k_norms<<<(n + k + 3) / 4, 256, 0, stream>>>(h, P, hsq, psq, n, H, k);
  k_msort<<<dim3(n / 64, (k + 63) / 64), dim3(256), 0, stream>>>(h, P, hsq, psq, perm, Ms, n, H, k);
  k_sink<<<NT, 1024, 0, stream>>>(Ms, meta, plD, plE, uF, vF, k, tm_last);
  k_epi<<<n, 256, 0, stream>>>(Ms, uF, vF, perm, tys, (float*)d_out, n, k);
}

// Round 12
// 536.325 us; speedup vs baseline: 1.0787x; 1.0787x over previous
//
#include <hip/hip_runtime.h>
#include <math.h>

#define NT 17
#define KCAP 300
#define NITER 30
#define TR 4        // rows per register tile (double-buffered)
#define LUMAX 1024  // max rows per type
// -1/tau * log2(e): B matrix is in base-2 log domain
#define MSCALE2 28.853900817779268f

typedef unsigned long long u64;

#define EX2(x) __builtin_amdgcn_exp2f(x)
#define LG2(x) __builtin_amdgcn_logf(x)
#if __has_builtin(__builtin_amdgcn_rcpf)
#define RCP(x) __builtin_amdgcn_rcpf(x)
#else
#define RCP(x) (1.0f / (x))
#endif

// ---- meta layout ----
// [0..16]   typeCount
// [32..48]  typeOff

__device__ inline float selu_f(float x) {
  const float scale = 1.0507009873554804934193349852946f;
  const float alpha = 1.6732632423543772848170429916717f;
  return x > 0.f ? scale * x : scale * alpha * (EX2(x * 1.4426950408889634f) - 1.f);
}

// fused histogram + prefix + scatter (single block)
__global__ __launch_bounds__(1024) void k_bucket(const int* __restrict__ jt, int n,
    int* __restrict__ meta, int* __restrict__ perm, int* __restrict__ tys) {
  __shared__ int hist[NT];
  __shared__ int off[NT];
  __shared__ int cnt[NT];
  int tid = threadIdx.x;
  if (tid < NT) { hist[tid] = 0; cnt[tid] = 0; }
  __syncthreads();
  for (int i = tid; i < n; i += 1024) atomicAdd(&hist[jt[i]], 1);
  __syncthreads();
  if (tid == 0) {
    int o = 0;
    for (int t = 0; t < NT; t++) {
      off[t] = o; meta[32 + t] = o; meta[t] = hist[t]; o += hist[t];
    }
  }
  __syncthreads();
  for (int i = tid; i < n; i += 1024) {
    int t = jt[i];
    int pos = off[t] + atomicAdd(&cnt[t], 1);
    perm[pos] = i;
    tys[pos] = t;
  }
}

// h = selu(emb @ W1 + b1)   (n x D) @ (D x H)
__global__ __launch_bounds__(256) void k_hgemm(const float* __restrict__ A,
    const float* __restrict__ B, const float* __restrict__ bias,
    float* __restrict__ C, int n, int D, int H) {
  __shared__ __align__(16) float As[16][68];
  __shared__ __align__(16) float Bs[16][68];
  int tid = threadIdx.x;
  int i0 = blockIdx.x * 64, j0 = blockIdx.y * 64;
  int tx = tid & 15, ty = tid >> 4;
  int aI = tid & 63, aK = (tid >> 6) << 2;
  int bJ = (tid & 15) << 2, bK = tid >> 4;
  float acc[4][4] = {};
  for (int k0 = 0; k0 < D; k0 += 16) {
    float4 av = *(const float4*)(A + (size_t)(i0 + aI) * D + k0 + aK);
    float4 bv = *(const float4*)(B + (size_t)(k0 + bK) * H + j0 + bJ);
    __syncthreads();
    As[aK + 0][aI] = av.x; As[aK + 1][aI] = av.y; As[aK + 2][aI] = av.z; As[aK + 3][aI] = av.w;
    *(float4*)(&Bs[bK][bJ]) = bv;
    __syncthreads();
#pragma unroll
    for (int kk = 0; kk < 16; kk++) {
      float4 a4 = *(float4*)(&As[kk][ty << 2]);
      float4 b4 = *(float4*)(&Bs[kk][tx << 2]);
      float aa[4] = {a4.x, a4.y, a4.z, a4.w};
      float bb[4] = {b4.x, b4.y, b4.z, b4.w};
#pragma unroll
      for (int p = 0; p < 4; p++)
#pragma unroll
        for (int q = 0; q < 4; q++)
          acc[p][q] = fmaf(aa[p], bb[q], acc[p][q]);
    }
  }
#pragma unroll
  for (int p = 0; p < 4; p++) {
    int i = i0 + (ty << 2) + p;
    float o[4];
#pragma unroll
    for (int q = 0; q < 4; q++) {
      int j = j0 + (tx << 2) + q;
      o[q] = selu_f(acc[p][q] + bias[j]);
    }
    *(float4*)(C + (size_t)i * H + j0 + (tx << 2)) = make_float4(o[0], o[1], o[2], o[3]);
  }
}

// Ms[r][j] = -max(0, |h_r|^2+|p_j|^2-2*dot)/tau*log2e, rows type-sorted.
// Row/proto norms computed IN-KERNEL from the same tile loads (k_norms fused).
__global__ __launch_bounds__(256) void k_msort(const float* __restrict__ h,
    const float* __restrict__ P, const int* __restrict__ perm,
    float* __restrict__ Ms, int n, int H, int k) {
  __shared__ __align__(16) float As[16][68];
  __shared__ __align__(16) float Bs[16][68];
  __shared__ float hp[4][64];
  __shared__ float pp[4][64];
  __shared__ int gIdx[64];
  int tid = threadIdx.x;
  int i0 = blockIdx.x * 64, j0 = blockIdx.y * 64;
  if (tid < 64) gIdx[tid] = perm[i0 + tid];
  __syncthreads();
  int tx = tid & 15, ty = tid >> 4;
  int aI = tid & 63, aK = (tid >> 6) << 2;
  int gA = gIdx[aI];
  bool bok = (j0 + aI) < k;
  const float* bRow = P + (size_t)(j0 + (bok ? aI : 0)) * H;
  float acc[4][4] = {};
  float ha = 0.f, pa = 0.f;
  for (int k0 = 0; k0 < H; k0 += 16) {
    float4 av = *(const float4*)(h + (size_t)gA * H + k0 + aK);
    float4 bv = *(const float4*)(bRow + k0 + aK);
    ha += av.x * av.x + av.y * av.y + av.z * av.z + av.w * av.w;
    pa += bv.x * bv.x + bv.y * bv.y + bv.z * bv.z + bv.w * bv.w;
    __syncthreads();
    As[aK + 0][aI] = av.x; As[aK + 1][aI] = av.y; As[aK + 2][aI] = av.z; As[aK + 3][aI] = av.w;
    Bs[aK + 0][aI] = bv.x; Bs[aK + 1][aI] = bv.y; Bs[aK + 2][aI] = bv.z; Bs[aK + 3][aI] = bv.w;
    __syncthreads();
#pragma unroll
    for (int kk = 0; kk < 16; kk++) {
      float4 a4 = *(float4*)(&As[kk][ty << 2]);
      float4 b4 = *(float4*)(&Bs[kk][tx << 2]);
      float aa[4] = {a4.x, a4.y, a4.z, a4.w};
      float bb[4] = {b4.x, b4.y, b4.z, b4.w};
#pragma unroll
      for (int p = 0; p < 4; p++)
#pragma unroll
        for (int q = 0; q < 4; q++)
          acc[p][q] = fmaf(aa[p], bb[q], acc[p][q]);
    }
  }
  int grp = tid >> 6;
  hp[grp][aI] = ha;
  pp[grp][aI] = pa;
  __syncthreads();
#pragma unroll
  for (int p = 0; p < 4; p++) {
    int rr = (ty << 2) + p;
    int r = i0 + rr;
    float hq = hp[0][rr] + hp[1][rr] + hp[2][rr] + hp[3][rr];
#pragma unroll
    for (int q = 0; q < 4; q++) {
      int jl = (tx << 2) + q;
      int j = j0 + jl;
      if (j < k) {
        float pq = pp[0][jl] + pp[1][jl] + pp[2][jl] + pp[3][jl];
        float d2 = hq + pq - 2.f * acc[p][q];
        d2 = fmaxf(d2, 0.f);
        Ms[(size_t)r * k + j] = -d2 * MSCALE2;
      }
    }
  }
}

// Persistent Sinkhorn, LINEAR domain, per-column max shift, one type per block.
// Reference schedule: u_m = 1/(K'v_{m-1} + tm/Σu_{m-1}). Register tiles are
// DOUBLE-BUFFERED (prefetch next tile during current tile's compute) to hide
// L2 latency. Σu exchanged via 4-deep epoch slots, consumed by wave 15
// overlapping other waves' first tile.
__global__ __launch_bounds__(1024) void k_sink(float* __restrict__ Ms,
    const int* __restrict__ meta,
    u64* __restrict__ plD, unsigned* __restrict__ plE,
    float* __restrict__ uF, float* __restrict__ vF,
    int k, float tm_last) {
  __shared__ __align__(16) float V[KCAP];      // v~ (and c_j during prologue)
  __shared__ __align__(16) float WP[16][304];  // per-wave col partials
  __shared__ float uarr[LUMAX];
  __shared__ float SU[16];
  __shared__ float w_sh;
  __shared__ int lvl_ep;
  int tid = threadIdx.x, lane = tid & 63, wv = tid >> 6;
  int t = blockIdx.x;
  int cR = meta[t];
  int s0 = meta[32 + t];
  int nt = (cR + TR - 1) / TR;
  int laneCnt = (lane < NT) ? meta[lane] : 0;
  bool l2v = (lane + 64) < (k >> 2);  // second float4 slot valid

  // ---- prologue: column max, then K' = exp2(B - c_j) in place ----
  {
    float4 cm0 = make_float4(-3e38f, -3e38f, -3e38f, -3e38f);
    float4 cm1 = cm0;
    for (int tile = wv; tile < nt; tile += 16) {
      int r0 = tile * TR;
#pragma unroll
      for (int rr = 0; rr < TR; rr++) {
        int rc = (r0 + rr < cR) ? (r0 + rr) : r0;
        const float4* rp = (const float4*)(Ms + (size_t)(s0 + rc) * k);
        float4 a0 = rp[lane];
        cm0.x = fmaxf(cm0.x, a0.x); cm0.y = fmaxf(cm0.y, a0.y);
        cm0.z = fmaxf(cm0.z, a0.z); cm0.w = fmaxf(cm0.w, a0.w);
        if (l2v) {
          float4 a1 = rp[lane + 64];
          cm1.x = fmaxf(cm1.x, a1.x); cm1.y = fmaxf(cm1.y, a1.y);
          cm1.z = fmaxf(cm1.z, a1.z); cm1.w = fmaxf(cm1.w, a1.w);
        }
      }
    }
    *(float4*)&WP[wv][4 * lane] = cm0;
    if (l2v) *(float4*)&WP[wv][4 * (lane + 64)] = cm1;
    __syncthreads();
    if (tid < k) {
      float c = WP[0][tid];
#pragma unroll
      for (int q = 1; q < 16; q++) c = fmaxf(c, WP[q][tid]);
      V[tid] = c;
    }
    __syncthreads();
    float4 c0 = *(const float4*)&V[4 * lane];
    float4 c1 = l2v ? *(const float4*)&V[4 * (lane + 64)] : c0;
    for (int tile = wv; tile < nt; tile += 16) {
      int r0 = tile * TR;
#pragma unroll
      for (int rr = 0; rr < TR; rr++) {
        int r = r0 + rr;
        if (r < cR) {
          float4* rp = (float4*)(Ms + (size_t)(s0 + r) * k);
          float4 a0 = rp[lane];
          a0.x = EX2(a0.x - c0.x); a0.y = EX2(a0.y - c0.y);
          a0.z = EX2(a0.z - c0.z); a0.w = EX2(a0.w - c0.w);
          rp[lane] = a0;
          if (l2v) {
            float4 a1 = rp[lane + 64];
            a1.x = EX2(a1.x - c1.x); a1.y = EX2(a1.y - c1.y);
            a1.z = EX2(a1.z - c1.z); a1.w = EX2(a1.w - c1.w);
            rp[lane + 64] = a1;
          }
        }
      }
    }
  }
  __syncthreads();
  if (tid < k) V[tid] = 0.f;  // v~ init (underflow-equivalent to reference)
  if (tid == 0) { w_sh = 1.f; lvl_ep = 0; }
  __syncthreads();

  for (int m = 0; m < NITER; m++) {
    int epoch = m + 1;
    // ---- wave 15: consume Σu_{m-1} -> w_sh; signal ----
    if (wv == 15) {
      if (m > 0) {
        int slot = (m - 1) & 3;
        unsigned want = (unsigned)m;
        bool need = (lane < NT) && (laneCnt > 0);
        for (;;) {
          bool ok = !need ||
              (__hip_atomic_load(&plE[((size_t)slot * NT + lane) * 16],
                                 __ATOMIC_RELAXED, __HIP_MEMORY_SCOPE_AGENT) == want);
          if (__all(ok)) break;
          __builtin_amdgcn_s_sleep(1);
        }
        u64 a = need
            ? __hip_atomic_load(&plD[((size_t)slot * NT + lane) * 8],
                                __ATOMIC_RELAXED, __HIP_MEMORY_SCOPE_AGENT)
            : 0ull;
        float s = need ? __uint_as_float((unsigned)a) : 0.f;
#pragma unroll
        for (int o = 32; o; o >>= 1) s += __shfl_xor(s, o);
        if (lane == 0) w_sh = tm_last / s;
      }
      if (lane == 0)
        __hip_atomic_store(&lvl_ep, epoch, __ATOMIC_RELEASE, __HIP_MEMORY_SCOPE_WORKGROUP);
    }
    // ---- phase A: double-buffered tiles (prefetch next during compute) ----
    float w = 0.f;
    bool haveW = (wv == 15);
    if (haveW) w = w_sh;
    float su = 0.f;
    float4 acc0 = make_float4(0.f, 0.f, 0.f, 0.f);
    float4 acc1 = acc0;
    float4 v0 = *(const float4*)&V[4 * lane];
    float4 v1 = l2v ? *(const float4*)&V[4 * (lane + 64)] : make_float4(0.f, 0.f, 0.f, 0.f);
    float4 a[TR][2], b[TR][2];

    auto loadTile = [&](int tile, float4 (&T)[TR][2]) {
      int r0 = tile * TR;
#pragma unroll
      for (int rr = 0; rr < TR; rr++) {
        int rc = (r0 + rr < cR) ? (r0 + rr) : r0;
        const float4* rp = (const float4*)(Ms + (size_t)(s0 + rc) * k);
        T[rr][0] = rp[lane];
        T[rr][1] = l2v ? rp[lane + 64] : make_float4(0.f, 0.f, 0.f, 0.f);
      }
    };
    auto computeTile = [&](int tile, float4 (&T)[TR][2]) {
      int r0 = tile * TR;
      float rs[TR];
#pragma unroll
      for (int rr = 0; rr < TR; rr++) {
        rs[rr] = T[rr][0].x * v0.x + T[rr][0].y * v0.y +
                 T[rr][0].z * v0.z + T[rr][0].w * v0.w +
                 T[rr][1].x * v1.x + T[rr][1].y * v1.y +
                 T[rr][1].z * v1.z + T[rr][1].w * v1.w;
      }
#pragma unroll
      for (int o = 32; o; o >>= 1) {
#pragma unroll
        for (int rr = 0; rr < TR; rr++) rs[rr] += __shfl_xor(rs[rr], o);
      }
      if (!haveW) {
        while (__hip_atomic_load(&lvl_ep, __ATOMIC_ACQUIRE, __HIP_MEMORY_SCOPE_WORKGROUP) < epoch)
          __builtin_amdgcn_s_sleep(1);
        w = w_sh;
        haveW = true;
      }
      float uu[TR];
#pragma unroll
      for (int rr = 0; rr < TR; rr++) {
        bool valid = (r0 + rr < cR);
        float u = RCP(rs[rr] + w);
        uu[rr] = valid ? u : 0.f;
        su += uu[rr];
        if (lane == 0 && valid) uarr[r0 + rr] = u;
      }
#pragma unroll
      for (int rr = 0; rr < TR; rr++) {
        acc0.x += T[rr][0].x * uu[rr]; acc0.y += T[rr][0].y * uu[rr];
        acc0.z += T[rr][0].z * uu[rr]; acc0.w += T[rr][0].w * uu[rr];
        acc1.x += T[rr][1].x * uu[rr]; acc1.y += T[rr][1].y * uu[rr];
        acc1.z += T[rr][1].z * uu[rr]; acc1.w += T[rr][1].w * uu[rr];
      }
    };

    int tile = wv;
    if (tile < nt) loadTile(tile, a);
    while (tile < nt) {
      int n1 = tile + 16;
      if (n1 < nt) loadTile(n1, b);
      computeTile(tile, a);
      if (n1 < nt) {
        int n2 = n1 + 16;
        if (n2 < nt) loadTile(n2, a);
        computeTile(n1, b);
      }
      tile += 32;
    }

    *(float4*)&WP[wv][4 * lane] = acc0;
    if (l2v) *(float4*)&WP[wv][4 * (lane + 64)] = acc1;
    if (lane == 0) SU[wv] = su;
    __syncthreads();
    // ---- wave 15: publish Σu_m (slot m&3) — overlaps phase B merge ----
    if (wv == 15) {
      float sp = (lane < 16) ? SU[lane] : 0.f;
#pragma unroll
      for (int o = 32; o; o >>= 1) sp += __shfl_xor(sp, o);
      int slot = m & 3;
      if (lane == 0)
        __hip_atomic_store(&plD[((size_t)slot * NT + t) * 8],
                           (u64)__float_as_uint(sp),
                           __ATOMIC_RELAXED, __HIP_MEMORY_SCOPE_AGENT);
      __builtin_amdgcn_s_waitcnt(0);  // data globally visible before epoch
      if (lane == 0)
        __hip_atomic_store(&plE[((size_t)slot * NT + t) * 16], (unsigned)epoch,
                           __ATOMIC_RELAXED, __HIP_MEMORY_SCOPE_AGENT);
    }
    // ---- phase B: 16-way col merge -> v~ ----
    if (tid < k) {
      float s = WP[0][tid];
#pragma unroll
      for (int q = 1; q < 16; q++) s += WP[q][tid];
      V[tid] = RCP(s);
    }
    __syncthreads();
  }
  for (int r = tid; r < cR; r += 1024) uF[s0 + r] = uarr[r];
  for (int j = tid; j < k; j += 1024) vF[(size_t)t * k + j] = V[j];
}

// epilogue (linear): T_rj = K'_rj·u_r·v~_j; logits = ln(T+1e-8); scatter T with
// incremental o0-mod-17 (one candidate slot per float4 group).
__global__ __launch_bounds__(256) void k_epi(const float* __restrict__ Ms,
    const float* __restrict__ uF, const float* __restrict__ vF,
    const int* __restrict__ perm, const int* __restrict__ tys,
    float* __restrict__ out, int n, int k) {
  __shared__ float vals[KCAP];
  int r = blockIdx.x;
  int i = perm[r], t = tys[r];
  float u = uF[r];
  const float* Krow = Ms + (size_t)r * k;
  const float* Vrow = vF + (size_t)t * k;
  for (int j = threadIdx.x; j < k; j += 256) vals[j] = Krow[j] * u * Vrow[j];
  __syncthreads();
  float* lg = out + (size_t)i * k;
  for (int j = threadIdx.x; j < k; j += 256)
    lg[j] = LG2(vals[j] + 1e-8f) * 0.6931471805599453f;
  int ns = k * NT;
  float* Trow = out + (size_t)n * k + (size_t)i * ns;
  if ((ns & 3) == 0) {
    int n4 = ns >> 2;
    int o0 = threadIdx.x << 2;
    int rmod = o0 % NT;
    for (int g4 = threadIdx.x; g4 < n4; g4 += 256, o0 += 1024) {
      int sstar = t - rmod; if (sstar < 0) sstar += NT;
      int j = (unsigned)(o0 + sstar) / (unsigned)NT;
      float vv = vals[j < k ? j : 0];
      float4 v;
      v.x = (sstar == 0) ? vv : 0.f;
      v.y = (sstar == 1) ? vv : 0.f;
      v.z = (sstar == 2) ? vv : 0.f;
      v.w = (sstar == 3) ? vv : 0.f;
      *(float4*)(Trow + o0) = v;
      rmod += 4; if (rmod >= NT) rmod -= NT;
      rmod %= NT;
    }
  } else {
    for (int o = threadIdx.x; o < ns; o += 256) {
      int j = o / NT;
      int tt = o - j * NT;
      Trow[o] = (tt == t) ? vals[j] : 0.f;
    }
  }
}

extern "C" void kernel_launch(void* const* d_in, const int* in_sizes, int n_in,
                              void* d_out, int out_size, void* d_ws, size_t ws_size,
                              hipStream_t stream) {
  const float* emb = (const float*)d_in[0];
  const float* W1  = (const float*)d_in[1];
  const float* b1  = (const float*)d_in[2];
  const float* P   = (const float*)d_in[3];
  const int*   jt  = (const int*)d_in[4];
  (void)n_in; (void)ws_size;

  const int n = in_sizes[4];
  const int H = in_sizes[2];
  const int D = in_sizes[1] / H;
  const int k = out_size / (n * (NT + 1));
  const int nslots = k * NT;
  const float tm_last = (float)((n - nslots) > 1 ? (n - nslots) : 1);

  char* w = (char*)d_ws;
  size_t off = 0;
  auto take = [&](size_t bytes) -> char* {
    char* p = w + off;
    off = (off + bytes + 255) & ~(size_t)255;
    return p;
  };
  int*      meta = (int*)take(4096);
  int*      perm = (int*)take((size_t)n * 4);
  int*      tys  = (int*)take((size_t)n * 4);
  float*    h    = (float*)take((size_t)n * H * 4);
  float*    Ms   = (float*)take((size_t)n * k * 4);
  u64*      plD  = (u64*)take((size_t)4 * NT * 64);
  unsigned* plE  = (unsigned*)take((size_t)4 * NT * 64);
  float*    uF   = (float*)take((size_t)n * 4);
  float*    vF   = (float*)take((size_t)NT * k * 4);

  (void)hipMemsetAsync(plE, 0, (size_t)4 * NT * 64, stream);
  k_bucket<<<1, 1024, 0, stream>>>(jt, n, meta, perm, tys);
  k_hgemm<<<dim3(n / 64, H / 64), dim3(256), 0, stream>>>(emb, W1, b1, h, n, D, H);
  k_msort<<<dim3(n / 64, (k + 63) / 64), dim3(256), 0, stream>>>(h, P, perm, Ms, n, H, k);
  k_sink<<<NT, 1024, 0, stream>>>(Ms, meta, plD, plE, uF, vF, k, tm_last);
  k_epi<<<n, 256, 0, stream>>>(Ms, uF, vF, perm, tys, (float*)d_out, n, k);
}

// Round 14
// 457.980 us; speedup vs baseline: 1.2632x; 1.1711x over previous
//
#include <hip/hip_runtime.h>
#include <math.h>

#define NT 17
#define NB 34       // 2 blocks per type
#define KCAP 300
#define NITER 30
#define TR 4        // rows per register tile (double-buffered)
// -1/tau * log2(e): B matrix is in base-2 log domain
#define MSCALE2 28.853900817779268f

typedef unsigned long long u64;
typedef float vfloat4 __attribute__((ext_vector_type(4)));

#define EX2(x) __builtin_amdgcn_exp2f(x)
#define LG2(x) __builtin_amdgcn_logf(x)
#if __has_builtin(__builtin_amdgcn_rcpf)
#define RCP(x) __builtin_amdgcn_rcpf(x)
#else
#define RCP(x) (1.0f / (x))
#endif

// ---- meta layout ----
// [0..16]   typeCount
// [32..48]  typeOff

__device__ inline float selu_f(float x) {
  const float scale = 1.0507009873554804934193349852946f;
  const float alpha = 1.6732632423543772848170429916717f;
  return x > 0.f ? scale * x : scale * alpha * (EX2(x * 1.4426950408889634f) - 1.f);
}

// fused histogram + prefix + scatter (single block)
__global__ __launch_bounds__(1024) void k_bucket(const int* __restrict__ jt, int n,
    int* __restrict__ meta, int* __restrict__ perm, int* __restrict__ tys) {
  __shared__ int hist[NT];
  __shared__ int off[NT];
  __shared__ int cnt[NT];
  int tid = threadIdx.x;
  if (tid < NT) { hist[tid] = 0; cnt[tid] = 0; }
  __syncthreads();
  for (int i = tid; i < n; i += 1024) atomicAdd(&hist[jt[i]], 1);
  __syncthreads();
  if (tid == 0) {
    int o = 0;
    for (int t = 0; t < NT; t++) {
      off[t] = o; meta[32 + t] = o; meta[t] = hist[t]; o += hist[t];
    }
  }
  __syncthreads();
  for (int i = tid; i < n; i += 1024) {
    int t = jt[i];
    int pos = off[t] + atomicAdd(&cnt[t], 1);
    perm[pos] = i;
    tys[pos] = t;
  }
}

// h = selu(emb @ W1 + b1)   (n x D) @ (D x H)
__global__ __launch_bounds__(256) void k_hgemm(const float* __restrict__ A,
    const float* __restrict__ B, const float* __restrict__ bias,
    float* __restrict__ C, int n, int D, int H) {
  __shared__ __align__(16) float As[16][68];
  __shared__ __align__(16) float Bs[16][68];
  int tid = threadIdx.x;
  int i0 = blockIdx.x * 64, j0 = blockIdx.y * 64;
  int tx = tid & 15, ty = tid >> 4;
  int aI = tid & 63, aK = (tid >> 6) << 2;
  int bJ = (tid & 15) << 2, bK = tid >> 4;
  float acc[4][4] = {};
  for (int k0 = 0; k0 < D; k0 += 16) {
    float4 av = *(const float4*)(A + (size_t)(i0 + aI) * D + k0 + aK);
    float4 bv = *(const float4*)(B + (size_t)(k0 + bK) * H + j0 + bJ);
    __syncthreads();
    As[aK + 0][aI] = av.x; As[aK + 1][aI] = av.y; As[aK + 2][aI] = av.z; As[aK + 3][aI] = av.w;
    *(float4*)(&Bs[bK][bJ]) = bv;
    __syncthreads();
#pragma unroll
    for (int kk = 0; kk < 16; kk++) {
      float4 a4 = *(float4*)(&As[kk][ty << 2]);
      float4 b4 = *(float4*)(&Bs[kk][tx << 2]);
      float aa[4] = {a4.x, a4.y, a4.z, a4.w};
      float bb[4] = {b4.x, b4.y, b4.z, b4.w};
#pragma unroll
      for (int p = 0; p < 4; p++)
#pragma unroll
        for (int q = 0; q < 4; q++)
          acc[p][q] = fmaf(aa[p], bb[q], acc[p][q]);
    }
  }
#pragma unroll
  for (int p = 0; p < 4; p++) {
    int i = i0 + (ty << 2) + p;
    float o[4];
#pragma unroll
    for (int q = 0; q < 4; q++) {
      int j = j0 + (tx << 2) + q;
      o[q] = selu_f(acc[p][q] + bias[j]);
    }
    *(float4*)(C + (size_t)i * H + j0 + (tx << 2)) = make_float4(o[0], o[1], o[2], o[3]);
  }
}

// Ms[r][j] = -max(0, |h_r|^2+|p_j|^2-2*dot)/tau*log2e, rows type-sorted.
// Row/proto norms computed in-kernel from the same tile loads.
__global__ __launch_bounds__(256) void k_msort(const float* __restrict__ h,
    const float* __restrict__ P, const int* __restrict__ perm,
    float* __restrict__ Ms, int n, int H, int k) {
  __shared__ __align__(16) float As[16][68];
  __shared__ __align__(16) float Bs[16][68];
  __shared__ float hp[4][64];
  __shared__ float pp[4][64];
  __shared__ int gIdx[64];
  int tid = threadIdx.x;
  int i0 = blockIdx.x * 64, j0 = blockIdx.y * 64;
  if (tid < 64) gIdx[tid] = perm[i0 + tid];
  __syncthreads();
  int tx = tid & 15, ty = tid >> 4;
  int aI = tid & 63, aK = (tid >> 6) << 2;
  int gA = gIdx[aI];
  bool bok = (j0 + aI) < k;
  const float* bRow = P + (size_t)(j0 + (bok ? aI : 0)) * H;
  float acc[4][4] = {};
  float ha = 0.f, pa = 0.f;
  for (int k0 = 0; k0 < H; k0 += 16) {
    float4 av = *(const float4*)(h + (size_t)gA * H + k0 + aK);
    float4 bv = *(const float4*)(bRow + k0 + aK);
    ha += av.x * av.x + av.y * av.y + av.z * av.z + av.w * av.w;
    pa += bv.x * bv.x + bv.y * bv.y + bv.z * bv.z + bv.w * bv.w;
    __syncthreads();
    As[aK + 0][aI] = av.x; As[aK + 1][aI] = av.y; As[aK + 2][aI] = av.z; As[aK + 3][aI] = av.w;
    Bs[aK + 0][aI] = bv.x; Bs[aK + 1][aI] = bv.y; Bs[aK + 2][aI] = bv.z; Bs[aK + 3][aI] = bv.w;
    __syncthreads();
#pragma unroll
    for (int kk = 0; kk < 16; kk++) {
      float4 a4 = *(float4*)(&As[kk][ty << 2]);
      float4 b4 = *(float4*)(&Bs[kk][tx << 2]);
      float aa[4] = {a4.x, a4.y, a4.z, a4.w};
      float bb[4] = {b4.x, b4.y, b4.z, b4.w};
#pragma unroll
      for (int p = 0; p < 4; p++)
#pragma unroll
        for (int q = 0; q < 4; q++)
          acc[p][q] = fmaf(aa[p], bb[q], acc[p][q]);
    }
  }
  int grp = tid >> 6;
  hp[grp][aI] = ha;
  pp[grp][aI] = pa;
  __syncthreads();
#pragma unroll
  for (int p = 0; p < 4; p++) {
    int rr = (ty << 2) + p;
    int r = i0 + rr;
    float hq = hp[0][rr] + hp[1][rr] + hp[2][rr] + hp[3][rr];
#pragma unroll
    for (int q = 0; q < 4; q++) {
      int jl = (tx << 2) + q;
      int j = j0 + jl;
      if (j < k) {
        float pq = pp[0][jl] + pp[1][jl] + pp[2][jl] + pp[3][jl];
        float d2 = hq + pq - 2.f * acc[p][q];
        d2 = fmaxf(d2, 0.f);
        Ms[(size_t)r * k + j] = -d2 * MSCALE2;
      }
    }
  }
}

// Persistent Sinkhorn, LINEAR domain, per-column max shift, TWO blocks per type
// (34 blocks, row-split halves). Per-iter pairwise exchange of 300-float column
// partials (publish -> partner epoch poll by tid0 -> LDS flag -> parallel UC
// reads -> V = rcp(own+partner)). Pair-consistent colmax via one-time prologue
// exchange. Global Σu via 34-lane lagged exchange overlapped with row pass.
__global__ __launch_bounds__(1024) void k_sink(float* __restrict__ Ms,
    const int* __restrict__ meta,
    float* __restrict__ cmD, unsigned* __restrict__ cmE,
    float* __restrict__ pcD, unsigned* __restrict__ pcE,
    float* __restrict__ suD, unsigned* __restrict__ suE,
    float* __restrict__ uF, float* __restrict__ vF,
    int k, float tm_last) {
  __shared__ __align__(16) float V[KCAP];      // full colmax, then v~
  __shared__ __align__(16) float Sown[KCAP];   // own half partial (colmax / colsum)
  __shared__ __align__(16) float WP[16][304];  // per-wave partials
  __shared__ float uarr[512];
  __shared__ float SU[16];
  __shared__ float w_sh;
  __shared__ int lvl_ep;
  __shared__ int pairflag;
  int tid = threadIdx.x, lane = tid & 63, wv = tid >> 6;
  int c = blockIdx.x;            // 0..33
  int t = c >> 1, hb = c & 1, prt = c ^ 1;
  int cRt = meta[t];
  int s0t = meta[32 + t];
  int h0 = (cRt + 1) >> 1;
  int rb = hb ? h0 : 0;
  int re = hb ? cRt : h0;
  int myR = re - rb;
  int s0 = s0t + rb;
  int nt = (myR + TR - 1) / TR;
  bool l2v = (lane + 64) < (k >> 2);

  if (tid == 0) { pairflag = 0; w_sh = 1.f; lvl_ep = 0; }

  // ---- prologue: half colmax -> pair exchange -> full colmax -> exp2 ----
  {
    float4 cm0 = make_float4(-3e38f, -3e38f, -3e38f, -3e38f);
    float4 cm1 = cm0;
    for (int tile = wv; tile < nt; tile += 16) {
      int r0 = tile * TR;
#pragma unroll
      for (int rr = 0; rr < TR; rr++) {
        int rc = (r0 + rr < myR) ? (r0 + rr) : r0;
        const float4* rp = (const float4*)(Ms + (size_t)(s0 + rc) * k);
        float4 a0 = rp[lane];
        cm0.x = fmaxf(cm0.x, a0.x); cm0.y = fmaxf(cm0.y, a0.y);
        cm0.z = fmaxf(cm0.z, a0.z); cm0.w = fmaxf(cm0.w, a0.w);
        if (l2v) {
          float4 a1 = rp[lane + 64];
          cm1.x = fmaxf(cm1.x, a1.x); cm1.y = fmaxf(cm1.y, a1.y);
          cm1.z = fmaxf(cm1.z, a1.z); cm1.w = fmaxf(cm1.w, a1.w);
        }
      }
    }
    *(float4*)&WP[wv][4 * lane] = cm0;
    if (l2v) *(float4*)&WP[wv][4 * (lane + 64)] = cm1;
    __syncthreads();
    if (tid < k) {
      float cmax = WP[0][tid];
#pragma unroll
      for (int q = 1; q < 16; q++) cmax = fmaxf(cmax, WP[q][tid]);
      Sown[tid] = cmax;
      __hip_atomic_store(&cmD[c * 304 + tid], cmax,
                         __ATOMIC_RELAXED, __HIP_MEMORY_SCOPE_AGENT);
    }
    __syncthreads();  // drains all cmD stores
    if (tid == 0) {
      __hip_atomic_store(&cmE[c * 16], 1u, __ATOMIC_RELAXED, __HIP_MEMORY_SCOPE_AGENT);
      while (__hip_atomic_load(&cmE[prt * 16], __ATOMIC_RELAXED, __HIP_MEMORY_SCOPE_AGENT) < 1u)
        __builtin_amdgcn_s_sleep(1);
      __hip_atomic_store(&pairflag, 1, __ATOMIC_RELEASE, __HIP_MEMORY_SCOPE_WORKGROUP);
    }
    if (tid < k) {
      while (__hip_atomic_load(&pairflag, __ATOMIC_ACQUIRE, __HIP_MEMORY_SCOPE_WORKGROUP) < 1)
        __builtin_amdgcn_s_sleep(1);
      float o = __hip_atomic_load(&cmD[prt * 304 + tid],
                                  __ATOMIC_RELAXED, __HIP_MEMORY_SCOPE_AGENT);
      V[tid] = fmaxf(Sown[tid], o);
    }
    __syncthreads();
    float4 c0 = *(const float4*)&V[4 * lane];
    float4 c1 = l2v ? *(const float4*)&V[4 * (lane + 64)] : c0;
    for (int tile = wv; tile < nt; tile += 16) {
      int r0 = tile * TR;
#pragma unroll
      for (int rr = 0; rr < TR; rr++) {
        int r = r0 + rr;
        if (r < myR) {
          float4* rp = (float4*)(Ms + (size_t)(s0 + r) * k);
          float4 a0 = rp[lane];
          a0.x = EX2(a0.x - c0.x); a0.y = EX2(a0.y - c0.y);
          a0.z = EX2(a0.z - c0.z); a0.w = EX2(a0.w - c0.w);
          rp[lane] = a0;
          if (l2v) {
            float4 a1 = rp[lane + 64];
            a1.x = EX2(a1.x - c1.x); a1.y = EX2(a1.y - c1.y);
            a1.z = EX2(a1.z - c1.z); a1.w = EX2(a1.w - c1.w);
            rp[lane + 64] = a1;
          }
        }
      }
    }
  }
  __syncthreads();
  if (tid < k) V[tid] = 0.f;  // v~ init (underflow-equivalent to reference)
  __syncthreads();

  for (int m = 0; m < NITER; m++) {
    int epoch = m + 1;
    int slot = m & 3;
    // ---- wave 15: consume Σu_{m-1} over 34 blocks -> w_sh; signal ----
    if (wv == 15) {
      if (m > 0) {
        int pslot = (m - 1) & 3;
        unsigned want = (unsigned)m;
        bool need = lane < NB;
        for (;;) {
          bool ok = !need ||
              (__hip_atomic_load(&suE[(pslot * NB + lane) * 16],
                                 __ATOMIC_RELAXED, __HIP_MEMORY_SCOPE_AGENT) >= want);
          if (__all(ok)) break;
          __builtin_amdgcn_s_sleep(1);
        }
        float s = need
            ? __hip_atomic_load(&suD[(pslot * NB + lane) * 16],
                                __ATOMIC_RELAXED, __HIP_MEMORY_SCOPE_AGENT)
            : 0.f;
#pragma unroll
        for (int o = 32; o; o >>= 1) s += __shfl_xor(s, o);
        if (lane == 0) w_sh = tm_last / s;
      }
      if (lane == 0)
        __hip_atomic_store(&lvl_ep, epoch, __ATOMIC_RELEASE, __HIP_MEMORY_SCOPE_WORKGROUP);
    }
    // ---- phase A: double-buffered register tiles over my half rows ----
    float w = 0.f;
    bool haveW = (wv == 15);
    if (haveW) w = w_sh;
    float su = 0.f;
    float4 acc0 = make_float4(0.f, 0.f, 0.f, 0.f);
    float4 acc1 = acc0;
    float4 v0 = *(const float4*)&V[4 * lane];
    float4 v1 = l2v ? *(const float4*)&V[4 * (lane + 64)] : make_float4(0.f, 0.f, 0.f, 0.f);
    float4 a[TR][2], b[TR][2];

    auto loadTile = [&](int tile, float4 (&T)[TR][2]) {
      int r0 = tile * TR;
#pragma unroll
      for (int rr = 0; rr < TR; rr++) {
        int rc = (r0 + rr < myR) ? (r0 + rr) : r0;
        const float4* rp = (const float4*)(Ms + (size_t)(s0 + rc) * k);
        T[rr][0] = rp[lane];
        T[rr][1] = l2v ? rp[lane + 64] : make_float4(0.f, 0.f, 0.f, 0.f);
      }
    };
    auto computeTile = [&](int tile, float4 (&T)[TR][2]) {
      int r0 = tile * TR;
      float rs[TR];
#pragma unroll
      for (int rr = 0; rr < TR; rr++) {
        rs[rr] = T[rr][0].x * v0.x + T[rr][0].y * v0.y +
                 T[rr][0].z * v0.z + T[rr][0].w * v0.w +
                 T[rr][1].x * v1.x + T[rr][1].y * v1.y +
                 T[rr][1].z * v1.z + T[rr][1].w * v1.w;
      }
#pragma unroll
      for (int o = 32; o; o >>= 1) {
#pragma unroll
        for (int rr = 0; rr < TR; rr++) rs[rr] += __shfl_xor(rs[rr], o);
      }
      if (!haveW) {
        while (__hip_atomic_load(&lvl_ep, __ATOMIC_ACQUIRE, __HIP_MEMORY_SCOPE_WORKGROUP) < epoch)
          __builtin_amdgcn_s_sleep(1);
        w = w_sh;
        haveW = true;
      }
      float uu[TR];
#pragma unroll
      for (int rr = 0; rr < TR; rr++) {
        bool valid = (r0 + rr < myR);
        float u = RCP(rs[rr] + w);
        uu[rr] = valid ? u : 0.f;
        su += uu[rr];
        if (lane == 0 && valid) uarr[r0 + rr] = u;
      }
#pragma unroll
      for (int rr = 0; rr < TR; rr++) {
        acc0.x += T[rr][0].x * uu[rr]; acc0.y += T[rr][0].y * uu[rr];
        acc0.z += T[rr][0].z * uu[rr]; acc0.w += T[rr][0].w * uu[rr];
        acc1.x += T[rr][1].x * uu[rr]; acc1.y += T[rr][1].y * uu[rr];
        acc1.z += T[rr][1].z * uu[rr]; acc1.w += T[rr][1].w * uu[rr];
      }
    };

    int tile = wv;
    if (tile < nt) loadTile(tile, a);
    while (tile < nt) {
      int n1 = tile + 16;
      if (n1 < nt) loadTile(n1, b);
      computeTile(tile, a);
      if (n1 < nt) {
        int n2 = n1 + 16;
        if (n2 < nt) loadTile(n2, a);
        computeTile(n1, b);
      }
      tile += 32;
    }
    if (!haveW) {  // blocks with zero tiles still need w consistency next iter
      while (__hip_atomic_load(&lvl_ep, __ATOMIC_ACQUIRE, __HIP_MEMORY_SCOPE_WORKGROUP) < epoch)
        __builtin_amdgcn_s_sleep(1);
      haveW = true;
    }

    *(float4*)&WP[wv][4 * lane] = acc0;
    if (l2v) *(float4*)&WP[wv][4 * (lane + 64)] = acc1;
    if (lane == 0) SU[wv] = su;
    __syncthreads();
    // ---- publish own col partial + block Σu ----
    if (tid < k) {
      float s = WP[0][tid];
#pragma unroll
      for (int q = 1; q < 16; q++) s += WP[q][tid];
      Sown[tid] = s;
      __hip_atomic_store(&pcD[(slot * NB + c) * 304 + tid], s,
                         __ATOMIC_RELAXED, __HIP_MEMORY_SCOPE_AGENT);
    }
    if (wv == 15) {
      float sp = (lane < 16) ? SU[lane] : 0.f;
#pragma unroll
      for (int o = 32; o; o >>= 1) sp += __shfl_xor(sp, o);
      if (lane == 0)
        __hip_atomic_store(&suD[(slot * NB + c) * 16], sp,
                           __ATOMIC_RELAXED, __HIP_MEMORY_SCOPE_AGENT);
      __builtin_amdgcn_s_waitcnt(0);
      if (lane == 0)
        __hip_atomic_store(&suE[(slot * NB + c) * 16], (unsigned)epoch,
                           __ATOMIC_RELAXED, __HIP_MEMORY_SCOPE_AGENT);
    }
    __syncthreads();  // drains all pcD stores
    // ---- pairwise combine: epoch handshake, partner read, V = rcp(sum) ----
    if (tid == 0) {
      __hip_atomic_store(&pcE[(slot * NB + c) * 16], (unsigned)epoch,
                         __ATOMIC_RELAXED, __HIP_MEMORY_SCOPE_AGENT);
      while (__hip_atomic_load(&pcE[(slot * NB + prt) * 16],
                               __ATOMIC_RELAXED, __HIP_MEMORY_SCOPE_AGENT) < (unsigned)epoch)
        __builtin_amdgcn_s_sleep(1);
      __hip_atomic_store(&pairflag, m + 2, __ATOMIC_RELEASE, __HIP_MEMORY_SCOPE_WORKGROUP);
    }
    if (tid < k) {
      while (__hip_atomic_load(&pairflag, __ATOMIC_ACQUIRE, __HIP_MEMORY_SCOPE_WORKGROUP) < m + 2)
        __builtin_amdgcn_s_sleep(1);
      float sp = __hip_atomic_load(&pcD[(slot * NB + prt) * 304 + tid],
                                   __ATOMIC_RELAXED, __HIP_MEMORY_SCOPE_AGENT);
      V[tid] = RCP(Sown[tid] + sp);
    }
    __syncthreads();
  }
  for (int r = tid; r < myR; r += 1024) uF[s0 + r] = uarr[r];
  if (hb == 0)
    for (int j = tid; j < k; j += 1024) vF[(size_t)t * k + j] = V[j];
}

// epilogue (linear): T_rj = K'_rj·u_r·v~_j; logits = ln(T+1e-8); T scatter with
// incremental mod-17 and NONTEMPORAL stores (write-only output).
__global__ __launch_bounds__(256) void k_epi(const float* __restrict__ Ms,
    const float* __restrict__ uF, const float* __restrict__ vF,
    const int* __restrict__ perm, const int* __restrict__ tys,
    float* __restrict__ out, int n, int k) {
  __shared__ float vals[KCAP];
  int r = blockIdx.x;
  int i = perm[r], t = tys[r];
  float u = uF[r];
  const float* Krow = Ms + (size_t)r * k;
  const float* Vrow = vF + (size_t)t * k;
  for (int j = threadIdx.x; j < k; j += 256) vals[j] = Krow[j] * u * Vrow[j];
  __syncthreads();
  float* lg = out + (size_t)i * k;
  for (int j = threadIdx.x; j < k; j += 256)
    __builtin_nontemporal_store(LG2(vals[j] + 1e-8f) * 0.6931471805599453f, &lg[j]);
  int ns = k * NT;
  float* Trow = out + (size_t)n * k + (size_t)i * ns;
  if ((ns & 3) == 0) {
    int n4 = ns >> 2;
    int o0 = threadIdx.x << 2;
    int rmod = o0 % NT;
    for (int g4 = threadIdx.x; g4 < n4; g4 += 256, o0 += 1024) {
      int sstar = t - rmod; if (sstar < 0) sstar += NT;
      int j = (unsigned)(o0 + sstar) / (unsigned)NT;
      float vv = vals[j < k ? j : 0];
      vfloat4 v;
      v.x = (sstar == 0) ? vv : 0.f;
      v.y = (sstar == 1) ? vv : 0.f;
      v.z = (sstar == 2) ? vv : 0.f;
      v.w = (sstar == 3) ? vv : 0.f;
      __builtin_nontemporal_store(v, (vfloat4*)(Trow + o0));
      rmod += 4; if (rmod >= NT) rmod -= NT;
    }
  } else {
    for (int o = threadIdx.x; o < ns; o += 256) {
      int j = o / NT;
      int tt = o - j * NT;
      Trow[o] = (tt == t) ? vals[j] : 0.f;
    }
  }
}

extern "C" void kernel_launch(void* const* d_in, const int* in_sizes, int n_in,
                              void* d_out, int out_size, void* d_ws, size_t ws_size,
                              hipStream_t stream) {
  const float* emb = (const float*)d_in[0];
  const float* W1  = (const float*)d_in[1];
  const float* b1  = (const float*)d_in[2];
  const float* P   = (const float*)d_in[3];
  const int*   jt  = (const int*)d_in[4];
  (void)n_in; (void)ws_size;

  const int n = in_sizes[4];
  const int H = in_sizes[2];
  const int D = in_sizes[1] / H;
  const int k = out_size / (n * (NT + 1));
  const int nslots = k * NT;
  const float tm_last = (float)((n - nslots) > 1 ? (n - nslots) : 1);

  char* w = (char*)d_ws;
  size_t off = 0;
  auto take = [&](size_t bytes) -> char* {
    char* p = w + off;
    off = (off + bytes + 255) & ~(size_t)255;
    return p;
  };
  int*      meta = (int*)take(4096);
  int*      perm = (int*)take((size_t)n * 4);
  int*      tys  = (int*)take((size_t)n * 4);
  float*    h    = (float*)take((size_t)n * H * 4);
  float*    Ms   = (float*)take((size_t)n * k * 4);
  float*    cmD  = (float*)take((size_t)NB * 304 * 4);
  unsigned* cmE  = (unsigned*)take((size_t)NB * 64);
  float*    pcD  = (float*)take((size_t)4 * NB * 304 * 4);
  unsigned* pcE  = (unsigned*)take((size_t)4 * NB * 64);
  float*    suD  = (float*)take((size_t)4 * NB * 64);
  unsigned* suE  = (unsigned*)take((size_t)4 * NB * 64);
  float*    uF   = (float*)take((size_t)n * 4);
  float*    vF   = (float*)take((size_t)NT * k * 4);

  (void)hipMemsetAsync(cmE, 0, (size_t)NB * 64, stream);
  (void)hipMemsetAsync(pcE, 0, (size_t)4 * NB * 64, stream);
  (void)hipMemsetAsync(suE, 0, (size_t)4 * NB * 64, stream);
  k_bucket<<<1, 1024, 0, stream>>>(jt, n, meta, perm, tys);
  k_hgemm<<<dim3(n / 64, H / 64), dim3(256), 0, stream>>>(emb, W1, b1, h, n, D, H);
  k_msort<<<dim3(n / 64, (k + 63) / 64), dim3(256), 0, stream>>>(h, P, perm, Ms, n, H, k);
  k_sink<<<NB, 1024, 0, stream>>>(Ms, meta, cmD, cmE, pcD, pcE, suD, suE,
                                  uF, vF, k, tm_last);
  k_epi<<<n, 256, 0, stream>>>(Ms, uF, vF, perm, tys, (float*)d_out, n, k);
}